// Round 1
// baseline (645.771 us; speedup 1.0000x reference)
//
#include <hip/hip_runtime.h>

#define N_TOTAL 204800
#define NB 1024
#define DIM 512
#define NC 52
#define BN_EPS 1e-5f

__device__ inline void f4add(float4& a, const float4 b) {
    a.x += b.x; a.y += b.y; a.z += b.z; a.w += b.w;
}

__device__ inline float bn_relu1(float v, int f,
                                 const float* __restrict__ s1, const float* __restrict__ s2,
                                 const float* __restrict__ g, const float* __restrict__ beta) {
    float m  = s1[f] * (1.0f / NB);
    float vv = s2[f] * (1.0f / NB) - m * m;
    float is = rsqrtf(vv + BN_EPS);
    float h  = g[f] * (v - m) * is + beta[f];
    return h > 0.f ? h : 0.f;
}

// ---------------- K0: prefix-scan of counts + dtype detect + zero stats ----
__global__ __launch_bounds__(1024) void k_scan(const int* __restrict__ bnn,
                                               int* __restrict__ offs,
                                               int* __restrict__ cnt,
                                               float* __restrict__ inv,
                                               float* __restrict__ stats /*2048 floats*/) {
    __shared__ int red[1024];
    int tid = threadIdx.x;
    int v32 = bnn[tid];
    red[tid] = v32;
    __syncthreads();
    for (int s = 512; s > 0; s >>= 1) {
        if (tid < s) red[tid] += red[tid + s];
        __syncthreads();
    }
    int total = red[0];
    __syncthreads();
    // if buffer is really int64 little-endian, low words sit at even int32 slots
    int c = (total == N_TOTAL) ? v32 : bnn[2 * tid];
    red[tid] = c;
    __syncthreads();
    for (int off = 1; off < 1024; off <<= 1) {
        int t = (tid >= off) ? red[tid - off] : 0;
        __syncthreads();
        red[tid] += t;
        __syncthreads();
    }
    offs[tid] = red[tid] - c;   // exclusive
    cnt[tid]  = c;
    inv[tid]  = 1.0f / (float)c;
    stats[tid]        = 0.0f;   // zero s1a,s2a,s1b,s2b
    stats[tid + 1024] = 0.0f;
}

// ---------------- K1: segment-mean pooling, 4-way column split -------------
// grid (NB, 4), 256 threads. Each block: 32 float4 columns (512 B/row) of one
// graph. 4096 blocks -> 16 blocks/CU with 8 resident -> dynamic rebalancing
// of the ragged per-graph counts; 32 waves/CU occupancy.
__global__ __launch_bounds__(256) void k_pool(const float* __restrict__ z,
                                              const int* __restrict__ offs,
                                              const int* __restrict__ cnt,
                                              const float* __restrict__ inv,
                                              float* __restrict__ X) {
    __shared__ float4 buf[3][32];
    int g  = blockIdx.x;
    int cc = blockIdx.y;               // column chunk 0..3
    int s0 = offs[g];
    int n  = cnt[g];
    float r = inv[g];
    int tid = threadIdx.x;
    int c4 = tid & 31;                 // float4 column within chunk
    int rp = tid >> 5;                 // row phase 0..7
    const float4* p = (const float4*)z + (size_t)s0 * 128 + cc * 32 + c4;
    float4 a0 = {0,0,0,0}, a1 = {0,0,0,0}, a2 = {0,0,0,0}, a3 = {0,0,0,0};
    int i = rp;
    for (; i + 56 < n; i += 64) {      // 8 loads in flight, rows stride 8
        float4 v0 = p[(size_t)(i +  0) * 128];
        float4 v1 = p[(size_t)(i +  8) * 128];
        float4 v2 = p[(size_t)(i + 16) * 128];
        float4 v3 = p[(size_t)(i + 24) * 128];
        float4 v4 = p[(size_t)(i + 32) * 128];
        float4 v5 = p[(size_t)(i + 40) * 128];
        float4 v6 = p[(size_t)(i + 48) * 128];
        float4 v7 = p[(size_t)(i + 56) * 128];
        f4add(a0, v0); f4add(a1, v1); f4add(a2, v2); f4add(a3, v3);
        f4add(a0, v4); f4add(a1, v5); f4add(a2, v6); f4add(a3, v7);
    }
    for (; i < n; i += 8) { float4 v = p[(size_t)i * 128]; f4add(a0, v); }
    f4add(a0, a1); f4add(a2, a3); f4add(a0, a2);
    // merge rp pairs within each wave: lane^32 holds rp^1, same c4
    a0.x += __shfl_xor(a0.x, 32); a0.y += __shfl_xor(a0.y, 32);
    a0.z += __shfl_xor(a0.z, 32); a0.w += __shfl_xor(a0.w, 32);
    int w    = tid >> 6;               // wave 0..3
    int lane = tid & 63;
    if (w > 0 && lane < 32) buf[w - 1][c4] = a0;
    __syncthreads();
    if (w == 0 && lane < 32) {
        f4add(a0, buf[0][c4]); f4add(a0, buf[1][c4]); f4add(a0, buf[2][c4]);
        a0.x *= r; a0.y *= r; a0.z *= r; a0.w *= r;
        ((float4*)X)[(size_t)g * 128 + cc * 32 + c4] = a0;
    }
}

// ---------------- K2: 32x64 tiled GEMM, reg-prefetch, BN-in, stats-out ----
// grid (NB/32, DIM/64) = 256 blocks (1/CU), 256 threads
template <bool BNA>
__global__ __launch_bounds__(256) void k_gemm32x64(const float* __restrict__ A,
                                                   const float* __restrict__ W,
                                                   const float* __restrict__ bias,
                                                   const float* __restrict__ ps1,
                                                   const float* __restrict__ ps2,
                                                   const float* __restrict__ gam,
                                                   const float* __restrict__ bet,
                                                   float* __restrict__ Y,
                                                   float* __restrict__ os1,
                                                   float* __restrict__ os2) {
    __shared__ float As[32][34];   // [k][row], pad 34 (even -> b64-aligned rows)
    __shared__ float Ws[32][68];   // [k][col], pad 68 (16B-aligned rows)
    int tid = threadIdx.x;
    int tx = tid & 15, ty = tid >> 4;
    int gr0 = blockIdx.x * 32;
    int gc0 = blockIdx.y * 64;

    // A-staging coords: 256 float4 = 32 rows x 8 k-quads
    int arow = tid >> 3;          // 0..31
    int akq  = tid & 7;           // 0..7
    // W-staging coords: 512 float4 = 32 k x 16 col-quads, 2 per thread
    int wk0 = tid >> 4;           // 0..15  (first half rows)
    int wcq = tid & 15;           // 0..15

    float acc[2][4] = {};

    // prefetch tile 0
    float4 ra  = *(const float4*)&A[(size_t)(gr0 + arow) * DIM + akq * 4];
    float4 rw0 = *(const float4*)&W[(size_t)wk0 * DIM + gc0 + wcq * 4];
    float4 rw1 = *(const float4*)&W[(size_t)(wk0 + 16) * DIM + gc0 + wcq * 4];

    for (int kt = 0; kt < 16; kt++) {
        // store staged regs to LDS (BN+ReLU applied to A here)
        float4 v = ra;
        if (BNA) {
            int f0 = kt * 32 + akq * 4;
            v.x = bn_relu1(v.x, f0 + 0, ps1, ps2, gam, bet);
            v.y = bn_relu1(v.y, f0 + 1, ps1, ps2, gam, bet);
            v.z = bn_relu1(v.z, f0 + 2, ps1, ps2, gam, bet);
            v.w = bn_relu1(v.w, f0 + 3, ps1, ps2, gam, bet);
        }
        As[akq * 4 + 0][arow] = v.x;
        As[akq * 4 + 1][arow] = v.y;
        As[akq * 4 + 2][arow] = v.z;
        As[akq * 4 + 3][arow] = v.w;
        *(float4*)&Ws[wk0][wcq * 4]      = rw0;
        *(float4*)&Ws[wk0 + 16][wcq * 4] = rw1;
        __syncthreads();

        if (kt < 15) {
            int k0 = (kt + 1) * 32;
            ra  = *(const float4*)&A[(size_t)(gr0 + arow) * DIM + k0 + akq * 4];
            rw0 = *(const float4*)&W[(size_t)(k0 + wk0) * DIM + gc0 + wcq * 4];
            rw1 = *(const float4*)&W[(size_t)(k0 + wk0 + 16) * DIM + gc0 + wcq * 4];
        }

#pragma unroll
        for (int k = 0; k < 32; k++) {
            float2 a = *(const float2*)&As[k][ty * 2];
            float4 w = *(const float4*)&Ws[k][tx * 4];
            acc[0][0] += a.x * w.x; acc[0][1] += a.x * w.y;
            acc[0][2] += a.x * w.z; acc[0][3] += a.x * w.w;
            acc[1][0] += a.y * w.x; acc[1][1] += a.y * w.y;
            acc[1][2] += a.y * w.z; acc[1][3] += a.y * w.w;
        }
        __syncthreads();
    }

    // epilogue: +bias, store, column stats (wave-reduced, then atomics)
    float4 b = *(const float4*)&bias[gc0 + tx * 4];
    float s[4] = {}, q[4] = {};
#pragma unroll
    for (int i = 0; i < 2; i++) {
        float4 y;
        y.x = acc[i][0] + b.x;
        y.y = acc[i][1] + b.y;
        y.z = acc[i][2] + b.z;
        y.w = acc[i][3] + b.w;
        *(float4*)&Y[(size_t)(gr0 + ty * 2 + i) * DIM + gc0 + tx * 4] = y;
        s[0] += y.x; q[0] += y.x * y.x;
        s[1] += y.y; q[1] += y.y * y.y;
        s[2] += y.z; q[2] += y.z * y.z;
        s[3] += y.w; q[3] += y.w * y.w;
    }
    // reduce across the 4 ty values within each wave (lanes differ by 16, 32)
#pragma unroll
    for (int j = 0; j < 4; j++) {
        s[j] += __shfl_xor(s[j], 16); s[j] += __shfl_xor(s[j], 32);
        q[j] += __shfl_xor(q[j], 16); q[j] += __shfl_xor(q[j], 32);
    }
    if ((ty & 3) == 0) {
#pragma unroll
        for (int j = 0; j < 4; j++) {
            atomicAdd(&os1[gc0 + tx * 4 + j], s[j]);
            atomicAdd(&os2[gc0 + tx * 4 + j], q[j]);
        }
    }
}

// ---------------- K3: final GEMM (BN2 fused on input) ---------------------
__global__ __launch_bounds__(256) void k_gemm3(const float* __restrict__ Y2,
                                               const float* __restrict__ W,
                                               const float* __restrict__ bias,
                                               const float* __restrict__ s1,
                                               const float* __restrict__ s2,
                                               const float* __restrict__ gam,
                                               const float* __restrict__ bet,
                                               float* __restrict__ out) {
    __shared__ float As[4][DIM];
    int tid = threadIdx.x;
    int r0 = blockIdx.x * 4;
#pragma unroll
    for (int it = 0; it < 2; it++) {
        int idx = it * 256 + tid;
        int row = idx >> 7;
        int cq  = idx & 127;
        int f   = cq * 4;
        float4 v = *(const float4*)&Y2[(size_t)(r0 + row) * DIM + f];
        v.x = bn_relu1(v.x, f + 0, s1, s2, gam, bet);
        v.y = bn_relu1(v.y, f + 1, s1, s2, gam, bet);
        v.z = bn_relu1(v.z, f + 2, s1, s2, gam, bet);
        v.w = bn_relu1(v.w, f + 3, s1, s2, gam, bet);
        *(float4*)&As[row][f] = v;
    }
    __syncthreads();
    int col = tid & 63;
    int row = tid >> 6;
    if (col < NC) {
        float acc = 0.f;
#pragma unroll 8
        for (int k = 0; k < DIM; k += 4) {
            float4 a = *(const float4*)&As[row][k];
            acc += a.x * W[(size_t)(k + 0) * NC + col];
            acc += a.y * W[(size_t)(k + 1) * NC + col];
            acc += a.z * W[(size_t)(k + 2) * NC + col];
            acc += a.w * W[(size_t)(k + 3) * NC + col];
        }
        out[(size_t)(r0 + row) * NC + col] = acc + bias[col];
    }
}

extern "C" void kernel_launch(void* const* d_in, const int* in_sizes, int n_in,
                              void* d_out, int out_size, void* d_ws, size_t ws_size,
                              hipStream_t stream) {
    const float* z   = (const float*)d_in[0];
    const int*   bnn = (const int*)d_in[1];
    const float* w1  = (const float*)d_in[2];
    const float* b1  = (const float*)d_in[3];
    const float* g1  = (const float*)d_in[4];
    const float* be1 = (const float*)d_in[5];
    const float* w2  = (const float*)d_in[6];
    const float* b2  = (const float*)d_in[7];
    const float* g2  = (const float*)d_in[8];
    const float* be2 = (const float*)d_in[9];
    const float* w3  = (const float*)d_in[10];
    const float* b3  = (const float*)d_in[11];

    int*   offs  = (int*)d_ws;
    int*   cnt   = offs + 1024;
    float* inv   = (float*)(cnt + 1024);
    float* stats = inv + 1024;             // 2048 floats: s1a|s2a|s1b|s2b
    float* X     = stats + 2048;
    float* Y1    = X  + (size_t)NB * DIM;
    float* Y2    = Y1 + (size_t)NB * DIM;
    float* out   = (float*)d_out;

    k_scan<<<1, 1024, 0, stream>>>(bnn, offs, cnt, inv, stats);
    k_pool<<<dim3(NB, 4), 256, 0, stream>>>(z, offs, cnt, inv, X);

    dim3 gg(NB / 32, DIM / 64);
    // layer 1: no BN on input; stats out -> s1a,s2a
    k_gemm32x64<false><<<gg, 256, 0, stream>>>(X, w1, b1,
                                               nullptr, nullptr, nullptr, nullptr,
                                               Y1, stats, stats + 512);
    // layer 2: BN1+ReLU fused on input; stats out -> s1b,s2b
    k_gemm32x64<true><<<gg, 256, 0, stream>>>(Y1, w2, b2,
                                              stats, stats + 512, g1, be1,
                                              Y2, stats + 1024, stats + 1536);
    // layer 3: BN2+ReLU fused on input
    k_gemm3<<<NB / 4, 256, 0, stream>>>(Y2, w3, b3,
                                        stats + 1024, stats + 1536, g2, be2, out);
}

// Round 3
// 623.479 us; speedup vs baseline: 1.0358x; 1.0358x over previous
//
#include <hip/hip_runtime.h>

#define N_TOTAL 204800
#define NB 1024
#define DIM 512
#define NC 52
#define BN_EPS 1e-5f

typedef float nf4 __attribute__((ext_vector_type(4)));   // native vector: OK for nontemporal builtins

__device__ inline void f4add(float4& a, const float4 b) {
    a.x += b.x; a.y += b.y; a.z += b.z; a.w += b.w;
}

__device__ inline float bn_relu1(float v, int f,
                                 const float* __restrict__ s1, const float* __restrict__ s2,
                                 const float* __restrict__ g, const float* __restrict__ beta) {
    float m  = s1[f] * (1.0f / NB);
    float vv = s2[f] * (1.0f / NB) - m * m;
    float is = rsqrtf(vv + BN_EPS);
    float h  = g[f] * (v - m) * is + beta[f];
    return h > 0.f ? h : 0.f;
}

// ---------------- K0: prefix-scan of counts (shfl-based, 2 barriers) -------
__global__ __launch_bounds__(1024) void k_scan(const int* __restrict__ bnn,
                                               int* __restrict__ offs,
                                               int* __restrict__ cnt,
                                               float* __restrict__ inv,
                                               float* __restrict__ stats /*2048 floats*/) {
    __shared__ int wtot[16];   // phase-1: wave sums of raw int32 words
    __shared__ int wsum[16];   // phase-2: wave sums of counts
    int tid  = threadIdx.x;
    int lane = tid & 63;
    int w    = tid >> 6;
    int v32  = bnn[tid];
    // total of raw words -> dtype detect (int64 counts have zero high words)
    int t = v32;
#pragma unroll
    for (int s = 1; s < 64; s <<= 1) t += __shfl_xor(t, s);
    if (lane == 0) wtot[w] = t;
    __syncthreads();
    int total = 0;
#pragma unroll
    for (int i = 0; i < 16; i++) total += wtot[i];
    int c = (total == N_TOTAL) ? v32 : bnn[2 * tid];  // int64 LE: low words at even slots
    // inclusive scan: shfl wave-scan + cross-wave partials
    int x = c;
#pragma unroll
    for (int s = 1; s < 64; s <<= 1) {
        int u = __shfl_up(x, s);
        if (lane >= s) x += u;
    }
    if (lane == 63) wsum[w] = x;
    __syncthreads();
    int pre = 0;
#pragma unroll
    for (int i = 0; i < 16; i++) if (i < w) pre += wsum[i];
    int incl = pre + x;
    offs[tid] = incl - c;   // exclusive
    cnt[tid]  = c;
    inv[tid]  = 1.0f / (float)c;
    stats[tid]        = 0.0f;   // zero s1a,s2a,s1b,s2b
    stats[tid + 1024] = 0.0f;
}

// ---------------- K1: segment-mean pooling, 4-way column split, NT loads ---
// grid (NB, 4), 256 threads. Each block: 32 float4 columns (512 B/row) of one
// graph. 4096 blocks -> dynamic rebalancing of ragged counts; 32 waves/CU.
// z is a 419 MB single-pass stream -> nontemporal loads (no L2/L3 pollution).
__global__ __launch_bounds__(256) void k_pool(const float* __restrict__ z,
                                              const int* __restrict__ offs,
                                              const int* __restrict__ cnt,
                                              const float* __restrict__ inv,
                                              float* __restrict__ X) {
    __shared__ nf4 buf[3][32];
    int g  = blockIdx.x;
    int cc = blockIdx.y;               // column chunk 0..3
    int s0 = offs[g];
    int n  = cnt[g];
    float r = inv[g];
    int tid = threadIdx.x;
    int c4 = tid & 31;                 // float4 column within chunk
    int rp = tid >> 5;                 // row phase 0..7
    const nf4* p = (const nf4*)z + (size_t)s0 * 128 + cc * 32 + c4;
    nf4 a0 = {0,0,0,0}, a1 = {0,0,0,0}, a2 = {0,0,0,0}, a3 = {0,0,0,0};
    int i = rp;
    for (; i + 56 < n; i += 64) {      // 8 loads in flight, rows stride 8
        nf4 v0 = __builtin_nontemporal_load(&p[(size_t)(i +  0) * 128]);
        nf4 v1 = __builtin_nontemporal_load(&p[(size_t)(i +  8) * 128]);
        nf4 v2 = __builtin_nontemporal_load(&p[(size_t)(i + 16) * 128]);
        nf4 v3 = __builtin_nontemporal_load(&p[(size_t)(i + 24) * 128]);
        nf4 v4 = __builtin_nontemporal_load(&p[(size_t)(i + 32) * 128]);
        nf4 v5 = __builtin_nontemporal_load(&p[(size_t)(i + 40) * 128]);
        nf4 v6 = __builtin_nontemporal_load(&p[(size_t)(i + 48) * 128]);
        nf4 v7 = __builtin_nontemporal_load(&p[(size_t)(i + 56) * 128]);
        a0 += v0; a1 += v1; a2 += v2; a3 += v3;
        a0 += v4; a1 += v5; a2 += v6; a3 += v7;
    }
    for (; i < n; i += 8) {
        a0 += __builtin_nontemporal_load(&p[(size_t)i * 128]);
    }
    a0 += a1; a2 += a3; a0 += a2;
    // merge rp pairs within each wave: lane^32 holds rp^1, same c4
    a0.x += __shfl_xor(a0.x, 32); a0.y += __shfl_xor(a0.y, 32);
    a0.z += __shfl_xor(a0.z, 32); a0.w += __shfl_xor(a0.w, 32);
    int w    = tid >> 6;               // wave 0..3
    int lane = tid & 63;
    if (w > 0 && lane < 32) buf[w - 1][c4] = a0;
    __syncthreads();
    if (w == 0 && lane < 32) {
        a0 += buf[0][c4]; a0 += buf[1][c4]; a0 += buf[2][c4];
        a0 *= r;
        ((nf4*)X)[(size_t)g * 128 + cc * 32 + c4] = a0;
    }
}

// ---------------- K2: 32x64 tiled GEMM, 512 threads (2 waves/SIMD) ---------
// grid (NB/32, DIM/64) = 256 blocks (1/CU), 512 threads, acc 2x2/thread
template <bool BNA>
__global__ __launch_bounds__(512) void k_gemm32x64(const float* __restrict__ A,
                                                   const float* __restrict__ W,
                                                   const float* __restrict__ bias,
                                                   const float* __restrict__ ps1,
                                                   const float* __restrict__ ps2,
                                                   const float* __restrict__ gam,
                                                   const float* __restrict__ bet,
                                                   float* __restrict__ Y,
                                                   float* __restrict__ os1,
                                                   float* __restrict__ os2) {
    __shared__ float As[32][34];   // [k][row], pad 34
    __shared__ float Ws[32][68];   // [k][col], pad 68
    int tid = threadIdx.x;
    int tx = tid & 31, ty = tid >> 5;   // tx: col pair 0..31, ty: row pair 0..15
    int gr0 = blockIdx.x * 32;
    int gc0 = blockIdx.y * 64;

    // A-staging: first 256 threads, one float4 each (32 rows x 8 k-quads)
    int arow = (tid & 255) >> 3;  // 0..31
    int akq  = tid & 7;           // 0..7
    // W-staging: all 512 threads, one float4 each (32 k x 16 col-quads)
    int wk  = tid >> 4;           // 0..31
    int wcq = tid & 15;           // 0..15

    float acc[2][2] = {};

    float4 ra = {0, 0, 0, 0};
    if (tid < 256) ra = *(const float4*)&A[(size_t)(gr0 + arow) * DIM + akq * 4];
    float4 rw = *(const float4*)&W[(size_t)wk * DIM + gc0 + wcq * 4];

    for (int kt = 0; kt < 16; kt++) {
        if (tid < 256) {
            float4 v = ra;
            if (BNA) {
                int f0 = kt * 32 + akq * 4;
                v.x = bn_relu1(v.x, f0 + 0, ps1, ps2, gam, bet);
                v.y = bn_relu1(v.y, f0 + 1, ps1, ps2, gam, bet);
                v.z = bn_relu1(v.z, f0 + 2, ps1, ps2, gam, bet);
                v.w = bn_relu1(v.w, f0 + 3, ps1, ps2, gam, bet);
            }
            As[akq * 4 + 0][arow] = v.x;
            As[akq * 4 + 1][arow] = v.y;
            As[akq * 4 + 2][arow] = v.z;
            As[akq * 4 + 3][arow] = v.w;
        }
        *(float4*)&Ws[wk][wcq * 4] = rw;
        __syncthreads();

        if (kt < 15) {
            int k0 = (kt + 1) * 32;
            if (tid < 256)
                ra = *(const float4*)&A[(size_t)(gr0 + arow) * DIM + k0 + akq * 4];
            rw = *(const float4*)&W[(size_t)(k0 + wk) * DIM + gc0 + wcq * 4];
        }

#pragma unroll
        for (int k = 0; k < 32; k++) {
            float2 a = *(const float2*)&As[k][ty * 2];
            float2 w = *(const float2*)&Ws[k][tx * 2];
            acc[0][0] += a.x * w.x; acc[0][1] += a.x * w.y;
            acc[1][0] += a.y * w.x; acc[1][1] += a.y * w.y;
        }
        __syncthreads();
    }

    // epilogue: +bias, store, column stats (wave-reduced, then atomics)
    float2 b = *(const float2*)&bias[gc0 + tx * 2];
    float s0 = 0, s1 = 0, q0 = 0, q1 = 0;
#pragma unroll
    for (int i = 0; i < 2; i++) {
        float2 y;
        y.x = acc[i][0] + b.x;
        y.y = acc[i][1] + b.y;
        *(float2*)&Y[(size_t)(gr0 + ty * 2 + i) * DIM + gc0 + tx * 2] = y;
        s0 += y.x; q0 += y.x * y.x;
        s1 += y.y; q1 += y.y * y.y;
    }
    // the 2 ty values within a wave sit at lane^32 with the same tx
    s0 += __shfl_xor(s0, 32); q0 += __shfl_xor(q0, 32);
    s1 += __shfl_xor(s1, 32); q1 += __shfl_xor(q1, 32);
    if ((tid & 63) < 32) {
        atomicAdd(&os1[gc0 + tx * 2 + 0], s0);
        atomicAdd(&os1[gc0 + tx * 2 + 1], s1);
        atomicAdd(&os2[gc0 + tx * 2 + 0], q0);
        atomicAdd(&os2[gc0 + tx * 2 + 1], q1);
    }
}

// ---------------- K3: final GEMM (BN2 fused on input) ---------------------
__global__ __launch_bounds__(256) void k_gemm3(const float* __restrict__ Y2,
                                               const float* __restrict__ W,
                                               const float* __restrict__ bias,
                                               const float* __restrict__ s1,
                                               const float* __restrict__ s2,
                                               const float* __restrict__ gam,
                                               const float* __restrict__ bet,
                                               float* __restrict__ out) {
    __shared__ float As[4][DIM];
    int tid = threadIdx.x;
    int r0 = blockIdx.x * 4;
#pragma unroll
    for (int it = 0; it < 2; it++) {
        int idx = it * 256 + tid;
        int row = idx >> 7;
        int cq  = idx & 127;
        int f   = cq * 4;
        float4 v = *(const float4*)&Y2[(size_t)(r0 + row) * DIM + f];
        v.x = bn_relu1(v.x, f + 0, s1, s2, gam, bet);
        v.y = bn_relu1(v.y, f + 1, s1, s2, gam, bet);
        v.z = bn_relu1(v.z, f + 2, s1, s2, gam, bet);
        v.w = bn_relu1(v.w, f + 3, s1, s2, gam, bet);
        *(float4*)&As[row][f] = v;
    }
    __syncthreads();
    int col = tid & 63;
    int row = tid >> 6;
    if (col < NC) {
        float acc = 0.f;
#pragma unroll 8
        for (int k = 0; k < DIM; k += 4) {
            float4 a = *(const float4*)&As[row][k];
            acc += a.x * W[(size_t)(k + 0) * NC + col];
            acc += a.y * W[(size_t)(k + 1) * NC + col];
            acc += a.z * W[(size_t)(k + 2) * NC + col];
            acc += a.w * W[(size_t)(k + 3) * NC + col];
        }
        out[(size_t)(r0 + row) * NC + col] = acc + bias[col];
    }
}

extern "C" void kernel_launch(void* const* d_in, const int* in_sizes, int n_in,
                              void* d_out, int out_size, void* d_ws, size_t ws_size,
                              hipStream_t stream) {
    const float* z   = (const float*)d_in[0];
    const int*   bnn = (const int*)d_in[1];
    const float* w1  = (const float*)d_in[2];
    const float* b1  = (const float*)d_in[3];
    const float* g1  = (const float*)d_in[4];
    const float* be1 = (const float*)d_in[5];
    const float* w2  = (const float*)d_in[6];
    const float* b2  = (const float*)d_in[7];
    const float* g2  = (const float*)d_in[8];
    const float* be2 = (const float*)d_in[9];
    const float* w3  = (const float*)d_in[10];
    const float* b3  = (const float*)d_in[11];

    int*   offs  = (int*)d_ws;
    int*   cnt   = offs + 1024;
    float* inv   = (float*)(cnt + 1024);
    float* stats = inv + 1024;             // 2048 floats: s1a|s2a|s1b|s2b
    float* X     = stats + 2048;
    float* Y1    = X  + (size_t)NB * DIM;
    float* Y2    = Y1 + (size_t)NB * DIM;
    float* out   = (float*)d_out;

    k_scan<<<1, 1024, 0, stream>>>(bnn, offs, cnt, inv, stats);
    k_pool<<<dim3(NB, 4), 256, 0, stream>>>(z, offs, cnt, inv, X);

    dim3 gg(NB / 32, DIM / 64);
    // layer 1: no BN on input; stats out -> s1a,s2a
    k_gemm32x64<false><<<gg, 512, 0, stream>>>(X, w1, b1,
                                               nullptr, nullptr, nullptr, nullptr,
                                               Y1, stats, stats + 512);
    // layer 2: BN1+ReLU fused on input; stats out -> s1b,s2b
    k_gemm32x64<true><<<gg, 512, 0, stream>>>(Y1, w2, b2,
                                              stats, stats + 512, g1, be1,
                                              Y2, stats + 1024, stats + 1536);
    // layer 3: BN2+ReLU fused on input
    k_gemm3<<<NB / 4, 256, 0, stream>>>(Y2, w3, b3,
                                        stats + 1024, stats + 1536, g2, be2, out);
}

// Round 4
// 619.868 us; speedup vs baseline: 1.0418x; 1.0058x over previous
//
#include <hip/hip_runtime.h>

#define N_TOTAL 204800
#define NB 1024
#define DIM 512
#define NC 52
#define BN_EPS 1e-5f

typedef float nf4 __attribute__((ext_vector_type(4)));   // native vector: OK for nontemporal builtins

__device__ inline float bn_relu1(float v, int f,
                                 const float* __restrict__ s1, const float* __restrict__ s2,
                                 const float* __restrict__ g, const float* __restrict__ beta) {
    float m  = s1[f] * (1.0f / NB);
    float vv = s2[f] * (1.0f / NB) - m * m;
    float is = rsqrtf(vv + BN_EPS);
    float h  = g[f] * (v - m) * is + beta[f];
    return h > 0.f ? h : 0.f;
}

// ---------------- K1: segment-mean pooling, self-computed offsets ----------
// grid (NB, 4), 256 threads. Each block: 32 float4 columns (512 B/row) of one
// graph. No separate scan kernel: counts buffer is 4-8 KB, L1/L2-resident, so
// each block sums counts[j<g] itself (~0.5 us, overlapped across 8 blocks/CU).
// z is a 419 MB single-pass stream -> nontemporal loads (no L2/L3 pollution).
__global__ __launch_bounds__(256) void k_pool(const float* __restrict__ z,
                                              const int* __restrict__ bnn,
                                              float* __restrict__ stats,
                                              float* __restrict__ X) {
    __shared__ nf4 buf[3][32];
    __shared__ int redA[4], redB[4];
    int g   = blockIdx.x;
    int cc  = blockIdx.y;              // column chunk 0..3
    int tid = threadIdx.x;
    int lane = tid & 63;
    int w    = tid >> 6;               // wave 0..3

    // ---- pass 1: total of raw int32 words -> dtype detect ----
    int t_all = 0;
#pragma unroll
    for (int k = 0; k < 4; k++) t_all += bnn[tid + k * 256];
#pragma unroll
    for (int s = 1; s < 64; s <<= 1) t_all += __shfl_xor(t_all, s);
    if (lane == 0) redA[w] = t_all;
    __syncthreads();
    bool is64 = (redA[0] + redA[1] + redA[2] + redA[3]) != N_TOTAL;

    // ---- pass 2: exclusive prefix (sum of counts j < g) ----
    int t_pre = 0;
#pragma unroll
    for (int k = 0; k < 4; k++) {
        int j = tid + k * 256;
        if (j < g) t_pre += is64 ? bnn[2 * j] : bnn[j];
    }
#pragma unroll
    for (int s = 1; s < 64; s <<= 1) t_pre += __shfl_xor(t_pre, s);
    if (lane == 0) redB[w] = t_pre;
    // zero BN stats (2048 floats) from the 8 (cc==0, g<8) blocks; pool
    // completes before gemm1's atomics are launched, so ordering is safe.
    if (cc == 0 && g < 8) stats[g * 256 + tid] = 0.0f;
    __syncthreads();
    int s0 = redB[0] + redB[1] + redB[2] + redB[3];
    int n  = is64 ? bnn[2 * g] : bnn[g];
    float r = 1.0f / (float)n;

    // ---- streaming accumulation ----
    int c4 = tid & 31;                 // float4 column within chunk
    int rp = tid >> 5;                 // row phase 0..7
    const nf4* p = (const nf4*)z + (size_t)s0 * 128 + cc * 32 + c4;
    nf4 a0 = {0,0,0,0}, a1 = {0,0,0,0}, a2 = {0,0,0,0}, a3 = {0,0,0,0};
    int i = rp;
    for (; i + 56 < n; i += 64) {      // 8 loads in flight, rows stride 8
        nf4 v0 = __builtin_nontemporal_load(&p[(size_t)(i +  0) * 128]);
        nf4 v1 = __builtin_nontemporal_load(&p[(size_t)(i +  8) * 128]);
        nf4 v2 = __builtin_nontemporal_load(&p[(size_t)(i + 16) * 128]);
        nf4 v3 = __builtin_nontemporal_load(&p[(size_t)(i + 24) * 128]);
        nf4 v4 = __builtin_nontemporal_load(&p[(size_t)(i + 32) * 128]);
        nf4 v5 = __builtin_nontemporal_load(&p[(size_t)(i + 40) * 128]);
        nf4 v6 = __builtin_nontemporal_load(&p[(size_t)(i + 48) * 128]);
        nf4 v7 = __builtin_nontemporal_load(&p[(size_t)(i + 56) * 128]);
        a0 += v0; a1 += v1; a2 += v2; a3 += v3;
        a0 += v4; a1 += v5; a2 += v6; a3 += v7;
    }
    for (; i < n; i += 8) {
        a0 += __builtin_nontemporal_load(&p[(size_t)i * 128]);
    }
    a0 += a1; a2 += a3; a0 += a2;
    // merge rp pairs within each wave: lane^32 holds rp^1, same c4
    a0.x += __shfl_xor(a0.x, 32); a0.y += __shfl_xor(a0.y, 32);
    a0.z += __shfl_xor(a0.z, 32); a0.w += __shfl_xor(a0.w, 32);
    if (w > 0 && lane < 32) buf[w - 1][c4] = a0;
    __syncthreads();
    if (w == 0 && lane < 32) {
        a0 += buf[0][c4]; a0 += buf[1][c4]; a0 += buf[2][c4];
        a0 *= r;
        ((nf4*)X)[(size_t)g * 128 + cc * 32 + c4] = a0;
    }
}

// ---------------- K2: 32x64 tiled GEMM, 512 threads (2 waves/SIMD) ---------
// grid (NB/32, DIM/64) = 256 blocks (1/CU), 512 threads, acc 2x2/thread
template <bool BNA>
__global__ __launch_bounds__(512) void k_gemm32x64(const float* __restrict__ A,
                                                   const float* __restrict__ W,
                                                   const float* __restrict__ bias,
                                                   const float* __restrict__ ps1,
                                                   const float* __restrict__ ps2,
                                                   const float* __restrict__ gam,
                                                   const float* __restrict__ bet,
                                                   float* __restrict__ Y,
                                                   float* __restrict__ os1,
                                                   float* __restrict__ os2) {
    __shared__ float As[32][34];   // [k][row], pad 34
    __shared__ float Ws[32][68];   // [k][col], pad 68
    int tid = threadIdx.x;
    int tx = tid & 31, ty = tid >> 5;   // tx: col pair 0..31, ty: row pair 0..15
    int gr0 = blockIdx.x * 32;
    int gc0 = blockIdx.y * 64;

    // A-staging: first 256 threads, one float4 each (32 rows x 8 k-quads)
    int arow = (tid & 255) >> 3;  // 0..31
    int akq  = tid & 7;           // 0..7
    // W-staging: all 512 threads, one float4 each (32 k x 16 col-quads)
    int wk  = tid >> 4;           // 0..31
    int wcq = tid & 15;           // 0..15

    float acc[2][2] = {};

    float4 ra = {0, 0, 0, 0};
    if (tid < 256) ra = *(const float4*)&A[(size_t)(gr0 + arow) * DIM + akq * 4];
    float4 rw = *(const float4*)&W[(size_t)wk * DIM + gc0 + wcq * 4];

    for (int kt = 0; kt < 16; kt++) {
        if (tid < 256) {
            float4 v = ra;
            if (BNA) {
                int f0 = kt * 32 + akq * 4;
                v.x = bn_relu1(v.x, f0 + 0, ps1, ps2, gam, bet);
                v.y = bn_relu1(v.y, f0 + 1, ps1, ps2, gam, bet);
                v.z = bn_relu1(v.z, f0 + 2, ps1, ps2, gam, bet);
                v.w = bn_relu1(v.w, f0 + 3, ps1, ps2, gam, bet);
            }
            As[akq * 4 + 0][arow] = v.x;
            As[akq * 4 + 1][arow] = v.y;
            As[akq * 4 + 2][arow] = v.z;
            As[akq * 4 + 3][arow] = v.w;
        }
        *(float4*)&Ws[wk][wcq * 4] = rw;
        __syncthreads();

        if (kt < 15) {
            int k0 = (kt + 1) * 32;
            if (tid < 256)
                ra = *(const float4*)&A[(size_t)(gr0 + arow) * DIM + k0 + akq * 4];
            rw = *(const float4*)&W[(size_t)(k0 + wk) * DIM + gc0 + wcq * 4];
        }

#pragma unroll
        for (int k = 0; k < 32; k++) {
            float2 a = *(const float2*)&As[k][ty * 2];
            float2 w = *(const float2*)&Ws[k][tx * 2];
            acc[0][0] += a.x * w.x; acc[0][1] += a.x * w.y;
            acc[1][0] += a.y * w.x; acc[1][1] += a.y * w.y;
        }
        __syncthreads();
    }

    // epilogue: +bias, store, column stats (wave-reduced, then atomics)
    float2 b = *(const float2*)&bias[gc0 + tx * 2];
    float s0 = 0, s1 = 0, q0 = 0, q1 = 0;
#pragma unroll
    for (int i = 0; i < 2; i++) {
        float2 y;
        y.x = acc[i][0] + b.x;
        y.y = acc[i][1] + b.y;
        *(float2*)&Y[(size_t)(gr0 + ty * 2 + i) * DIM + gc0 + tx * 2] = y;
        s0 += y.x; q0 += y.x * y.x;
        s1 += y.y; q1 += y.y * y.y;
    }
    // the 2 ty values within a wave sit at lane^32 with the same tx
    s0 += __shfl_xor(s0, 32); q0 += __shfl_xor(q0, 32);
    s1 += __shfl_xor(s1, 32); q1 += __shfl_xor(q1, 32);
    if ((tid & 63) < 32) {
        atomicAdd(&os1[gc0 + tx * 2 + 0], s0);
        atomicAdd(&os1[gc0 + tx * 2 + 1], s1);
        atomicAdd(&os2[gc0 + tx * 2 + 0], q0);
        atomicAdd(&os2[gc0 + tx * 2 + 1], q1);
    }
}

// ---------------- K3: final GEMM (BN2 fused on input) ---------------------
__global__ __launch_bounds__(256) void k_gemm3(const float* __restrict__ Y2,
                                               const float* __restrict__ W,
                                               const float* __restrict__ bias,
                                               const float* __restrict__ s1,
                                               const float* __restrict__ s2,
                                               const float* __restrict__ gam,
                                               const float* __restrict__ bet,
                                               float* __restrict__ out) {
    __shared__ float As[4][DIM];
    int tid = threadIdx.x;
    int r0 = blockIdx.x * 4;
#pragma unroll
    for (int it = 0; it < 2; it++) {
        int idx = it * 256 + tid;
        int row = idx >> 7;
        int cq  = idx & 127;
        int f   = cq * 4;
        float4 v = *(const float4*)&Y2[(size_t)(r0 + row) * DIM + f];
        v.x = bn_relu1(v.x, f + 0, s1, s2, gam, bet);
        v.y = bn_relu1(v.y, f + 1, s1, s2, gam, bet);
        v.z = bn_relu1(v.z, f + 2, s1, s2, gam, bet);
        v.w = bn_relu1(v.w, f + 3, s1, s2, gam, bet);
        *(float4*)&As[row][f] = v;
    }
    __syncthreads();
    int col = tid & 63;
    int row = tid >> 6;
    if (col < NC) {
        float acc = 0.f;
#pragma unroll 8
        for (int k = 0; k < DIM; k += 4) {
            float4 a = *(const float4*)&As[row][k];
            acc += a.x * W[(size_t)(k + 0) * NC + col];
            acc += a.y * W[(size_t)(k + 1) * NC + col];
            acc += a.z * W[(size_t)(k + 2) * NC + col];
            acc += a.w * W[(size_t)(k + 3) * NC + col];
        }
        out[(size_t)(r0 + row) * NC + col] = acc + bias[col];
    }
}

extern "C" void kernel_launch(void* const* d_in, const int* in_sizes, int n_in,
                              void* d_out, int out_size, void* d_ws, size_t ws_size,
                              hipStream_t stream) {
    const float* z   = (const float*)d_in[0];
    const int*   bnn = (const int*)d_in[1];
    const float* w1  = (const float*)d_in[2];
    const float* b1  = (const float*)d_in[3];
    const float* g1  = (const float*)d_in[4];
    const float* be1 = (const float*)d_in[5];
    const float* w2  = (const float*)d_in[6];
    const float* b2  = (const float*)d_in[7];
    const float* g2  = (const float*)d_in[8];
    const float* be2 = (const float*)d_in[9];
    const float* w3  = (const float*)d_in[10];
    const float* b3  = (const float*)d_in[11];

    float* stats = (float*)d_ws;           // 2048 floats: s1a|s2a|s1b|s2b
    float* X     = stats + 2048;
    float* Y1    = X  + (size_t)NB * DIM;
    float* Y2    = Y1 + (size_t)NB * DIM;
    float* out   = (float*)d_out;

    k_pool<<<dim3(NB, 4), 256, 0, stream>>>(z, bnn, stats, X);

    dim3 gg(NB / 32, DIM / 64);
    // layer 1: no BN on input; stats out -> s1a,s2a
    k_gemm32x64<false><<<gg, 512, 0, stream>>>(X, w1, b1,
                                               nullptr, nullptr, nullptr, nullptr,
                                               Y1, stats, stats + 512);
    // layer 2: BN1+ReLU fused on input; stats out -> s1b,s2b
    k_gemm32x64<true><<<gg, 512, 0, stream>>>(Y1, w2, b2,
                                              stats, stats + 512, g1, be1,
                                              Y2, stats + 1024, stats + 1536);
    // layer 3: BN2+ReLU fused on input
    k_gemm3<<<NB / 4, 256, 0, stream>>>(Y2, w3, b3,
                                        stats + 1024, stats + 1536, g2, be2, out);
}